// Round 7
// baseline (913.389 us; speedup 1.0000x reference)
//
#include <hip/hip_runtime.h>
#include <math.h>

#define ATTN_SCALE 0.17677669529663687f   // 32^-0.5

typedef __attribute__((ext_vector_type(8))) _Float16 f16x8;
typedef __attribute__((ext_vector_type(4))) _Float16 f16x4;
typedef __attribute__((ext_vector_type(4))) float f32x4;

__device__ __forceinline__ f32x4 mfma16(f16x8 a, f16x8 b, f32x4 c) {
  return __builtin_amdgcn_mfma_f32_16x16x32_f16(a, b, c, 0, 0, 0);
}

// XOR-swizzled LDS index helpers (return f16 element index).
// byte ^= (row&7)<<4 : spreads 8 consecutive rows across 8 distinct 16B slots,
// keeps 16B/8B alignment (only bits >=4 touched).
__device__ __forceinline__ int SX(int r, int c) {  // 256 f16/row (xh, qk)
  int b = (r << 9) + (c << 1);
  return (b ^ ((r & 7) << 4)) >> 1;
}
__device__ __forceinline__ int SV(int r, int c) {  // 64 f16/row (vt)
  int b = (r << 7) + (c << 1);
  return (b ^ ((r & 7) << 4)) >> 1;
}
__device__ __forceinline__ int SO(int r, int c) {  // 128 f16/row (obuf)
  int b = (r << 8) + (c << 1);
  return (b ^ ((r & 7) << 4)) >> 1;
}

__device__ __forceinline__ float wave_sum64(float v) {
#pragma unroll
  for (int m = 1; m < 64; m <<= 1) v += __shfl_xor(v, m, 64);
  return v;
}

// ---------------- dynamic position bias MLP ----------------
__global__ void dpb_kernel(const float* __restrict__ w1, const float* __restrict__ b1,
                           const float* __restrict__ g1, const float* __restrict__ bb1,
                           const float* __restrict__ w2, const float* __restrict__ b2,
                           const float* __restrict__ g2, const float* __restrict__ bb2,
                           const float* __restrict__ w3, const float* __restrict__ b3,
                           const float* __restrict__ g3, const float* __restrict__ bb3,
                           const float* __restrict__ w4, const float* __restrict__ b4,
                           float* __restrict__ biases) {
  const int r = blockIdx.x;
  const int lane = threadIdx.x;
  const float rel0 = (float)(r / 17 - 8);
  const float rel1 = (float)(r % 17 - 8);

  float h = rel0 * w1[lane] + rel1 * w1[64 + lane] + b1[lane];
  {
    const float mean = wave_sum64(h) * (1.f / 64.f);
    const float d = h - mean;
    const float var = wave_sum64(d * d) * (1.f / 64.f);
    h = fmaxf(d * rsqrtf(var + 1e-3f) * g1[lane] + bb1[lane], 0.f);
  }
  float h2 = b2[lane];
  for (int i = 0; i < 64; ++i) h2 += __shfl(h, i, 64) * w2[i * 64 + lane];
  {
    const float mean = wave_sum64(h2) * (1.f / 64.f);
    const float d = h2 - mean;
    const float var = wave_sum64(d * d) * (1.f / 64.f);
    h2 = fmaxf(d * rsqrtf(var + 1e-3f) * g2[lane] + bb2[lane], 0.f);
  }
  float h3 = b3[lane];
  for (int i = 0; i < 64; ++i) h3 += __shfl(h2, i, 64) * w3[i * 64 + lane];
  {
    const float mean = wave_sum64(h3) * (1.f / 64.f);
    const float d = h3 - mean;
    const float var = wave_sum64(d * d) * (1.f / 64.f);
    h3 = fmaxf(d * rsqrtf(var + 1e-3f) * g3[lane] + bb3[lane], 0.f);
  }
  float p = wave_sum64(h3 * w4[lane]);
  if (lane == 0) biases[r] = p + b4[0];
}

// expand 289-entry table to Bexp[qt][kt] (64x64 f32) in global ws
__global__ void expand_bias(const float* __restrict__ biases, float* __restrict__ bexp) {
  const int qt = blockIdx.x, kt = threadIdx.x;
  const int idx = ((qt >> 3) - (kt >> 3) + 7) * 15 + ((qt & 7) - (kt & 7) + 7);
  bexp[qt * 64 + kt] = biases[idx];
}

// ---------------- weight prep: transpose + fp16 hi/lo split ----------------
__global__ void prep_wqkv(const float* __restrict__ w, _Float16* __restrict__ th,
                          _Float16* __restrict__ tl) {
  const int o = blockIdx.x;    // 0..767
  const int k = threadIdx.x;   // 0..255
  float v = w[k * 768 + o];
  if (o < 256) v *= ATTN_SCALE;
  const _Float16 hi = (_Float16)v;
  th[o * 256 + k] = hi;
  tl[o * 256 + k] = (_Float16)(v - (float)hi);
}

__global__ void prep_wout(const float* __restrict__ w, _Float16* __restrict__ th,
                          _Float16* __restrict__ tl) {
  const int o = blockIdx.x;
  const int k = threadIdx.x;
  const float v = w[k * 256 + o];
  const _Float16 hi = (_Float16)v;
  th[o * 256 + k] = hi;
  tl[o * 256 + k] = (_Float16)(v - (float)hi);
}

// ---------------- fused LN + windowed attention + out-proj ----------------
// 1 window/block, 512 threads = 8 waves. 80 KB LDS exactly -> 2 blocks/CU.
// Two 4-head passes; XOR-swizzled pad-free LDS.
__global__ __launch_bounds__(512, 4) void attn_mfma3(
    const float* __restrict__ x, const float* __restrict__ gamma,
    const float* __restrict__ beta,
    const _Float16* __restrict__ wqh, const _Float16* __restrict__ wql,
    const _Float16* __restrict__ woh, const _Float16* __restrict__ wol,
    const float* __restrict__ bout, const float* __restrict__ bexp,
    float* __restrict__ out) {
  __shared__ __align__(16) _Float16 smem[40960];   // 81920 B exactly
  _Float16* xh = smem;            // [64][256] LN'd x
  _Float16* qk = smem + 16384;    // [64][256] Q(cols 0-127)|K(128-255) -> P[64][4*64]
  _Float16* vo = smem + 32768;    // [128][64] V^T  ->  [64][128] O

  const int tid = threadIdx.x;
  const int lane = tid & 63;
  const int w = tid >> 6;        // wave 0..7
  const int l15 = lane & 15;
  const int khi = lane >> 4;     // 0..3

  const int wi = blockIdx.x;
  const int bb_ = wi >> 8;
  const int hb = (wi >> 4) & 15;
  const int wb = wi & 15;

  // ---- LN (eps 1e-5) -> xh fp16 ----
  {
    const int t = tid >> 3;
    const int d0 = (tid & 7) * 32;
    const int row = hb * 8 + (t >> 3);
    const int col = wb * 8 + (t & 7);
    const float* gp = x + ((((size_t)bb_ * 128 + row) * 128 + col) * 256 + d0);
    float vv[32];
    float sum = 0.f, ssq = 0.f;
#pragma unroll
    for (int j = 0; j < 8; ++j) {
      const float4 v4 = *(const float4*)(gp + j * 4);
      vv[j * 4 + 0] = v4.x; vv[j * 4 + 1] = v4.y;
      vv[j * 4 + 2] = v4.z; vv[j * 4 + 3] = v4.w;
      sum += v4.x + v4.y + v4.z + v4.w;
      ssq += v4.x * v4.x + v4.y * v4.y + v4.z * v4.z + v4.w * v4.w;
    }
#pragma unroll
    for (int mm = 1; mm < 8; mm <<= 1) {
      sum += __shfl_xor(sum, mm, 64);
      ssq += __shfl_xor(ssq, mm, 64);
    }
    const float mean = sum * (1.f / 256.f);
    const float var = ssq * (1.f / 256.f) - mean * mean;
    const float rstd = rsqrtf(var + 1e-5f);
#pragma unroll
    for (int q = 0; q < 8; ++q) {
      const float4 g4 = *(const float4*)(gamma + d0 + q * 4);
      const float4 b4 = *(const float4*)(beta + d0 + q * 4);
      vv[q * 4 + 0] = (vv[q * 4 + 0] - mean) * rstd * g4.x + b4.x;
      vv[q * 4 + 1] = (vv[q * 4 + 1] - mean) * rstd * g4.y + b4.y;
      vv[q * 4 + 2] = (vv[q * 4 + 2] - mean) * rstd * g4.z + b4.z;
      vv[q * 4 + 3] = (vv[q * 4 + 3] - mean) * rstd * g4.w + b4.w;
    }
#pragma unroll
    for (int q = 0; q < 4; ++q) {
      f16x8 pk;
#pragma unroll
      for (int e = 0; e < 8; ++e) pk[e] = (_Float16)vv[q * 8 + e];
      *(f16x8*)&xh[SX(t, d0 + q * 8)] = pk;
    }
  }

  f32x4 yacc[2][4];
#pragma unroll
  for (int j = 0; j < 2; ++j)
#pragma unroll
    for (int m = 0; m < 4; ++m) yacc[j][m] = (f32x4){0.f, 0.f, 0.f, 0.f};

  __syncthreads();   // xh ready

  const f32x4 zz = (f32x4){0.f, 0.f, 0.f, 0.f};

  for (int p = 0; p < 2; ++p) {      // two 4-head passes
    // ---- P1: QKV for heads 4p..4p+3. 24 coltiles of 16; wave owns 3 ----
    {
      f32x4 acc[3][4];
#pragma unroll
      for (int jj = 0; jj < 3; ++jj)
#pragma unroll
        for (int m = 0; m < 4; ++m) acc[jj][m] = zz;

      int gbase[3];
#pragma unroll
      for (int jj = 0; jj < 3; ++jj) {
        const int t = w * 3 + jj;
        const int kind = t >> 3, sub = t & 7;   // kind 0=Q,1=K,2=V
        gbase[jj] = (kind * 256 + p * 128 + sub * 16 + l15) * 256;
      }
      const int ko0 = khi * 8;
#pragma unroll
      for (int kt = 0; kt < 8; ++kt) {
        const int ko = kt * 32 + ko0;
        const f16x8 a0 = *(const f16x8*)&xh[SX(0 * 16 + l15, ko)];
        const f16x8 a1 = *(const f16x8*)&xh[SX(1 * 16 + l15, ko)];
        const f16x8 a2 = *(const f16x8*)&xh[SX(2 * 16 + l15, ko)];
        const f16x8 a3 = *(const f16x8*)&xh[SX(3 * 16 + l15, ko)];
#pragma unroll
        for (int jj = 0; jj < 3; ++jj) {
          const f16x8 bh = *(const f16x8*)&wqh[gbase[jj] + ko];
          const f16x8 bl = *(const f16x8*)&wql[gbase[jj] + ko];
          acc[jj][0] = mfma16(a0, bh, acc[jj][0]); acc[jj][0] = mfma16(a0, bl, acc[jj][0]);
          acc[jj][1] = mfma16(a1, bh, acc[jj][1]); acc[jj][1] = mfma16(a1, bl, acc[jj][1]);
          acc[jj][2] = mfma16(a2, bh, acc[jj][2]); acc[jj][2] = mfma16(a2, bl, acc[jj][2]);
          acc[jj][3] = mfma16(a3, bh, acc[jj][3]); acc[jj][3] = mfma16(a3, bl, acc[jj][3]);
        }
      }
      // store Q/K (scalar) and V^T (packed b64)
#pragma unroll
      for (int jj = 0; jj < 3; ++jj) {
        const int t = w * 3 + jj;
        const int kind = t >> 3, sub = t & 7;
        if (kind == 0) {
#pragma unroll
          for (int m = 0; m < 4; ++m)
#pragma unroll
            for (int rg = 0; rg < 4; ++rg)
              qk[SX(m * 16 + khi * 4 + rg, sub * 16 + l15)] = (_Float16)acc[jj][m][rg];
        } else if (kind == 1) {
#pragma unroll
          for (int m = 0; m < 4; ++m)
#pragma unroll
            for (int rg = 0; rg < 4; ++rg)
              qk[SX(m * 16 + khi * 4 + rg, 128 + sub * 16 + l15)] = (_Float16)acc[jj][m][rg];
        } else {
#pragma unroll
          for (int m = 0; m < 4; ++m) {
            f16x4 pv;
#pragma unroll
            for (int rg = 0; rg < 4; ++rg) pv[rg] = (_Float16)acc[jj][m][rg];
            *(f16x4*)&vo[SV(sub * 16 + l15, m * 16 + khi * 4)] = pv;
          }
        }
      }
    }
    __syncthreads();   // Q/K/V ready

    // ---- P2: attention; 2 waves per head (hl = w>>1, qhalf = w&1) ----
    {
      const int hl = w >> 1, qh = w & 1;
      f16x8 ka[4], qb[2];
      f32x4 bias[2][4];
#pragma unroll
      for (int kt = 0; kt < 4; ++kt)
        ka[kt] = *(const f16x8*)&qk[SX(kt * 16 + l15, 128 + hl * 32 + khi * 8)];
#pragma unroll
      for (int n = 0; n < 2; ++n)
        qb[n] = *(const f16x8*)&qk[SX((qh * 2 + n) * 16 + l15, hl * 32 + khi * 8)];
#pragma unroll
      for (int n = 0; n < 2; ++n)
#pragma unroll
        for (int kt = 0; kt < 4; ++kt)
          bias[n][kt] = *(const f32x4*)&bexp[(qh * 32 + n * 16 + l15) * 64 + kt * 16 + khi * 4];
      __syncthreads();   // all Q/K frag reads done -> P overwrite safe

      // simT[ktok][qtok] = K·Q^T + bias (bias as MFMA C-operand)
      f32x4 st[4][2];
#pragma unroll
      for (int kt = 0; kt < 4; ++kt)
#pragma unroll
        for (int n = 0; n < 2; ++n)
          st[kt][n] = mfma16(ka[kt], qb[n], bias[n][kt]);

      // softmax over ktok: 16 in-lane + reduce across khi groups
#pragma unroll
      for (int n = 0; n < 2; ++n) {
        float mx = st[0][n][0];
#pragma unroll
        for (int kt = 0; kt < 4; ++kt)
#pragma unroll
          for (int rg = 0; rg < 4; ++rg) mx = fmaxf(mx, st[kt][n][rg]);
        mx = fmaxf(mx, __shfl_xor(mx, 16, 64));
        mx = fmaxf(mx, __shfl_xor(mx, 32, 64));
        float sm = 0.f;
#pragma unroll
        for (int kt = 0; kt < 4; ++kt)
#pragma unroll
          for (int rg = 0; rg < 4; ++rg) {
            const float e = __expf(st[kt][n][rg] - mx);
            st[kt][n][rg] = e;
            sm += e;
          }
        sm += __shfl_xor(sm, 16, 64);
        sm += __shfl_xor(sm, 32, 64);
        const float inv = 1.f / sm;
#pragma unroll
        for (int kt = 0; kt < 4; ++kt)
#pragma unroll
          for (int rg = 0; rg < 4; ++rg) st[kt][n][rg] *= inv;
      }

      // write P[qt][kt] into qk cols hl*64.. (head-disjoint), packed b64
#pragma unroll
      for (int n = 0; n < 2; ++n)
#pragma unroll
        for (int kt = 0; kt < 4; ++kt) {
          f16x4 pp;
#pragma unroll
          for (int rg = 0; rg < 4; ++rg) pp[rg] = (_Float16)st[kt][n][rg];
          *(f16x4*)&qk[SX(qh * 32 + n * 16 + l15, hl * 64 + kt * 16 + khi * 4)] = pp;
        }

      // O^T = V^T · P^T (same-wave P read-back; vt rows of own head)
      f32x4 ot[2][2];
#pragma unroll
      for (int dt = 0; dt < 2; ++dt)
#pragma unroll
        for (int n = 0; n < 2; ++n) ot[dt][n] = zz;
#pragma unroll
      for (int k2 = 0; k2 < 2; ++k2) {
        const f16x8 va0 = *(const f16x8*)&vo[SV(hl * 32 + 0 * 16 + l15, k2 * 32 + khi * 8)];
        const f16x8 va1 = *(const f16x8*)&vo[SV(hl * 32 + 1 * 16 + l15, k2 * 32 + khi * 8)];
        const f16x8 pb0 = *(const f16x8*)&qk[SX(qh * 32 + 0 * 16 + l15, hl * 64 + k2 * 32 + khi * 8)];
        const f16x8 pb1 = *(const f16x8*)&qk[SX(qh * 32 + 1 * 16 + l15, hl * 64 + k2 * 32 + khi * 8)];
        ot[0][0] = mfma16(va0, pb0, ot[0][0]);
        ot[0][1] = mfma16(va0, pb1, ot[0][1]);
        ot[1][0] = mfma16(va1, pb0, ot[1][0]);
        ot[1][1] = mfma16(va1, pb1, ot[1][1]);
      }
      __syncthreads();   // all V^T reads done -> O overwrite of vo safe

      // O[tok][hl*32+dh] into vo-as-obuf [64][128], packed b64
#pragma unroll
      for (int n = 0; n < 2; ++n)
#pragma unroll
        for (int dt = 0; dt < 2; ++dt) {
          f16x4 ov;
#pragma unroll
          for (int rg = 0; rg < 4; ++rg) ov[rg] = (_Float16)ot[dt][n][rg];
          *(f16x4*)&vo[SO(qh * 32 + n * 16 + l15, hl * 32 + dt * 16 + khi * 4)] = ov;
        }
    }
    __syncthreads();   // O ready

    // ---- P3: Y += O @ Wout (k-range p*128..p*128+127); wave owns 2 coltiles ----
    {
#pragma unroll
      for (int kt = 0; kt < 4; ++kt) {
        const int ko = kt * 32 + khi * 8;
        const f16x8 a0 = *(const f16x8*)&vo[SO(0 * 16 + l15, ko)];
        const f16x8 a1 = *(const f16x8*)&vo[SO(1 * 16 + l15, ko)];
        const f16x8 a2 = *(const f16x8*)&vo[SO(2 * 16 + l15, ko)];
        const f16x8 a3 = *(const f16x8*)&vo[SO(3 * 16 + l15, ko)];
#pragma unroll
        for (int j = 0; j < 2; ++j) {
          const int oc = (w * 2 + j) * 16 + l15;
          const int base = oc * 256 + p * 128 + ko;
          const f16x8 bh = *(const f16x8*)&woh[base];
          const f16x8 bl = *(const f16x8*)&wol[base];
          yacc[j][0] = mfma16(a0, bh, yacc[j][0]); yacc[j][0] = mfma16(a0, bl, yacc[j][0]);
          yacc[j][1] = mfma16(a1, bh, yacc[j][1]); yacc[j][1] = mfma16(a1, bl, yacc[j][1]);
          yacc[j][2] = mfma16(a2, bh, yacc[j][2]); yacc[j][2] = mfma16(a2, bl, yacc[j][2]);
          yacc[j][3] = mfma16(a3, bh, yacc[j][3]); yacc[j][3] = mfma16(a3, bl, yacc[j][3]);
        }
      }
    }
    __syncthreads();   // obuf reads done -> next pass P1 may overwrite qk/vo
  }

  // ---- epilogue: + b_out, un-window, store fp32 ----
#pragma unroll
  for (int j = 0; j < 2; ++j) {
    const int oc = (w * 2 + j) * 16 + l15;
    const float bo = bout[oc];
#pragma unroll
    for (int m = 0; m < 4; ++m)
#pragma unroll
      for (int rg = 0; rg < 4; ++rg) {
        const int tok = m * 16 + khi * 4 + rg;
        const int row = hb * 8 + (tok >> 3);
        const int col = wb * 8 + (tok & 7);
        out[(((size_t)bb_ * 128 + row) * 128 + col) * 256 + oc] = yacc[j][m][rg] + bo;
      }
  }
}

extern "C" void kernel_launch(void* const* d_in, const int* in_sizes, int n_in,
                              void* d_out, int out_size, void* d_ws, size_t ws_size,
                              hipStream_t stream) {
  const float* x    = (const float*)d_in[0];
  const float* ng   = (const float*)d_in[1];
  const float* nb   = (const float*)d_in[2];
  const float* wqkv = (const float*)d_in[3];
  const float* wout = (const float*)d_in[4];
  const float* bout = (const float*)d_in[5];
  const float* dw1  = (const float*)d_in[6];
  const float* db1  = (const float*)d_in[7];
  const float* dg1  = (const float*)d_in[8];
  const float* dbb1 = (const float*)d_in[9];
  const float* dw2  = (const float*)d_in[10];
  const float* db2  = (const float*)d_in[11];
  const float* dg2  = (const float*)d_in[12];
  const float* dbb2 = (const float*)d_in[13];
  const float* dw3  = (const float*)d_in[14];
  const float* db3  = (const float*)d_in[15];
  const float* dg3  = (const float*)d_in[16];
  const float* dbb3 = (const float*)d_in[17];
  const float* dw4  = (const float*)d_in[18];
  const float* db4  = (const float*)d_in[19];

  char* ws = (char*)d_ws;
  float* biases  = (float*)ws;                          //    2048 B (289 used)
  _Float16* wqh  = (_Float16*)(ws + 2048);              //  393216 B
  _Float16* wql  = (_Float16*)(ws + 2048 + 393216);     //  393216 B
  _Float16* woh  = (_Float16*)(ws + 2048 + 786432);     //  131072 B
  _Float16* wol  = (_Float16*)(ws + 2048 + 917504);     //  131072 B
  float* bexp    = (float*)(ws + 1050624);              //   16384 B -> 1,067,008 total

  float* out = (float*)d_out;

  dpb_kernel<<<289, 64, 0, stream>>>(dw1, db1, dg1, dbb1, dw2, db2, dg2, dbb2,
                                     dw3, db3, dg3, dbb3, dw4, db4, biases);
  expand_bias<<<64, 64, 0, stream>>>(biases, bexp);
  prep_wqkv<<<768, 256, 0, stream>>>(wqkv, wqh, wql);
  prep_wout<<<256, 256, 0, stream>>>(wout, woh, wol);
  attn_mfma3<<<2048, 512, 0, stream>>>(x, ng, nb, wqh, wql, woh, wol, bout, bexp, out);
}

// Round 9
// 775.851 us; speedup vs baseline: 1.1773x; 1.1773x over previous
//
#include <hip/hip_runtime.h>
#include <math.h>

#define ATTN_SCALE 0.17677669529663687f   // 32^-0.5

typedef __attribute__((ext_vector_type(8))) _Float16 f16x8;
typedef __attribute__((ext_vector_type(4))) _Float16 f16x4;
typedef __attribute__((ext_vector_type(4))) float f32x4;

__device__ __forceinline__ f32x4 mfma16(f16x8 a, f16x8 b, f32x4 c) {
  return __builtin_amdgcn_mfma_f32_16x16x32_f16(a, b, c, 0, 0, 0);
}

// XOR-swizzled LDS index helpers (return f16 element index).
__device__ __forceinline__ int SX(int r, int c) {  // 256 f16/row (xh, qk)
  int b = (r << 9) + (c << 1);
  return (b ^ ((r & 7) << 4)) >> 1;
}
__device__ __forceinline__ int SV(int r, int c) {  // 64 f16/row (vt)
  int b = (r << 7) + (c << 1);
  return (b ^ ((r & 7) << 4)) >> 1;
}
__device__ __forceinline__ int SO(int r, int c) {  // 128 f16/row (obuf)
  int b = (r << 8) + (c << 1);
  return (b ^ ((r & 7) << 4)) >> 1;
}

__device__ __forceinline__ float wave_sum64(float v) {
#pragma unroll
  for (int m = 1; m < 64; m <<= 1) v += __shfl_xor(v, m, 64);
  return v;
}

// ---------------- dynamic position bias MLP ----------------
__global__ void dpb_kernel(const float* __restrict__ w1, const float* __restrict__ b1,
                           const float* __restrict__ g1, const float* __restrict__ bb1,
                           const float* __restrict__ w2, const float* __restrict__ b2,
                           const float* __restrict__ g2, const float* __restrict__ bb2,
                           const float* __restrict__ w3, const float* __restrict__ b3,
                           const float* __restrict__ g3, const float* __restrict__ bb3,
                           const float* __restrict__ w4, const float* __restrict__ b4,
                           float* __restrict__ biases) {
  const int r = blockIdx.x;
  const int lane = threadIdx.x;
  const float rel0 = (float)(r / 17 - 8);
  const float rel1 = (float)(r % 17 - 8);

  float h = rel0 * w1[lane] + rel1 * w1[64 + lane] + b1[lane];
  {
    const float mean = wave_sum64(h) * (1.f / 64.f);
    const float d = h - mean;
    const float var = wave_sum64(d * d) * (1.f / 64.f);
    h = fmaxf(d * rsqrtf(var + 1e-3f) * g1[lane] + bb1[lane], 0.f);
  }
  float h2 = b2[lane];
  for (int i = 0; i < 64; ++i) h2 += __shfl(h, i, 64) * w2[i * 64 + lane];
  {
    const float mean = wave_sum64(h2) * (1.f / 64.f);
    const float d = h2 - mean;
    const float var = wave_sum64(d * d) * (1.f / 64.f);
    h2 = fmaxf(d * rsqrtf(var + 1e-3f) * g2[lane] + bb2[lane], 0.f);
  }
  float h3 = b3[lane];
  for (int i = 0; i < 64; ++i) h3 += __shfl(h2, i, 64) * w3[i * 64 + lane];
  {
    const float mean = wave_sum64(h3) * (1.f / 64.f);
    const float d = h3 - mean;
    const float var = wave_sum64(d * d) * (1.f / 64.f);
    h3 = fmaxf(d * rsqrtf(var + 1e-3f) * g3[lane] + bb3[lane], 0.f);
  }
  float p = wave_sum64(h3 * w4[lane]);
  if (lane == 0) biases[r] = p + b4[0];
}

// expand 289-entry table to Bexp[qt][kt] (64x64 f32) in global ws
__global__ void expand_bias(const float* __restrict__ biases, float* __restrict__ bexp) {
  const int qt = blockIdx.x, kt = threadIdx.x;
  const int idx = ((qt >> 3) - (kt >> 3) + 7) * 15 + ((qt & 7) - (kt & 7) + 7);
  bexp[qt * 64 + kt] = biases[idx];
}

// ---------------- weight prep: transpose + fp16 hi/lo split ----------------
__global__ void prep_wqkv(const float* __restrict__ w, _Float16* __restrict__ th,
                          _Float16* __restrict__ tl) {
  const int o = blockIdx.x;    // 0..767
  const int k = threadIdx.x;   // 0..255
  float v = w[k * 768 + o];
  if (o < 256) v *= ATTN_SCALE;
  const _Float16 hi = (_Float16)v;
  th[o * 256 + k] = hi;
  tl[o * 256 + k] = (_Float16)(v - (float)hi);
}

__global__ void prep_wout(const float* __restrict__ w, _Float16* __restrict__ th,
                          _Float16* __restrict__ tl) {
  const int o = blockIdx.x;
  const int k = threadIdx.x;
  const float v = w[k * 256 + o];
  const _Float16 hi = (_Float16)v;
  th[o * 256 + k] = hi;
  tl[o * 256 + k] = (_Float16)(v - (float)hi);
}

// ---------------- fused LN + windowed attention + out-proj ----------------
// 1 window/block, 512 threads = 8 waves. 80 KB LDS exactly -> 2 blocks/CU.
// NOTE: __launch_bounds__ 2nd arg behaves as CUDA min-blocks/CU on hipcc:
// (512,4) forced VGPR=64 -> massive spill (R7: FETCH 727MB, WRITE 1073MB).
// (512,2) allows 128 VGPR = exactly 2 blocks/CU with our 80KB LDS.
__global__ __launch_bounds__(512, 2) void attn_mfma3(
    const float* __restrict__ x, const float* __restrict__ gamma,
    const float* __restrict__ beta,
    const _Float16* __restrict__ wqh, const _Float16* __restrict__ wql,
    const _Float16* __restrict__ woh, const _Float16* __restrict__ wol,
    const float* __restrict__ bout, const float* __restrict__ bexp,
    float* __restrict__ out) {
  __shared__ __align__(16) _Float16 smem[40960];   // 81920 B exactly
  _Float16* xh = smem;            // [64][256] LN'd x
  _Float16* qk = smem + 16384;    // [64][256] Q(cols 0-127)|K(128-255) -> P[64][4*64]
  _Float16* vo = smem + 32768;    // [128][64] V^T  ->  [64][128] O

  const int tid = threadIdx.x;
  const int lane = tid & 63;
  const int w = tid >> 6;        // wave 0..7
  const int l15 = lane & 15;
  const int khi = lane >> 4;     // 0..3

  const int wi = blockIdx.x;
  const int bb_ = wi >> 8;
  const int hb = (wi >> 4) & 15;
  const int wb = wi & 15;

  // ---- LN (eps 1e-5) -> xh fp16 ----
  {
    const int t = tid >> 3;
    const int d0 = (tid & 7) * 32;
    const int row = hb * 8 + (t >> 3);
    const int col = wb * 8 + (t & 7);
    const float* gp = x + ((((size_t)bb_ * 128 + row) * 128 + col) * 256 + d0);
    float vv[32];
    float sum = 0.f, ssq = 0.f;
#pragma unroll
    for (int j = 0; j < 8; ++j) {
      const float4 v4 = *(const float4*)(gp + j * 4);
      vv[j * 4 + 0] = v4.x; vv[j * 4 + 1] = v4.y;
      vv[j * 4 + 2] = v4.z; vv[j * 4 + 3] = v4.w;
      sum += v4.x + v4.y + v4.z + v4.w;
      ssq += v4.x * v4.x + v4.y * v4.y + v4.z * v4.z + v4.w * v4.w;
    }
#pragma unroll
    for (int mm = 1; mm < 8; mm <<= 1) {
      sum += __shfl_xor(sum, mm, 64);
      ssq += __shfl_xor(ssq, mm, 64);
    }
    const float mean = sum * (1.f / 256.f);
    const float var = ssq * (1.f / 256.f) - mean * mean;
    const float rstd = rsqrtf(var + 1e-5f);
#pragma unroll
    for (int q = 0; q < 8; ++q) {
      const float4 g4 = *(const float4*)(gamma + d0 + q * 4);
      const float4 b4 = *(const float4*)(beta + d0 + q * 4);
      vv[q * 4 + 0] = (vv[q * 4 + 0] - mean) * rstd * g4.x + b4.x;
      vv[q * 4 + 1] = (vv[q * 4 + 1] - mean) * rstd * g4.y + b4.y;
      vv[q * 4 + 2] = (vv[q * 4 + 2] - mean) * rstd * g4.z + b4.z;
      vv[q * 4 + 3] = (vv[q * 4 + 3] - mean) * rstd * g4.w + b4.w;
    }
#pragma unroll
    for (int q = 0; q < 4; ++q) {
      f16x8 pk;
#pragma unroll
      for (int e = 0; e < 8; ++e) pk[e] = (_Float16)vv[q * 8 + e];
      *(f16x8*)&xh[SX(t, d0 + q * 8)] = pk;
    }
  }

  f32x4 yacc[2][4];
#pragma unroll
  for (int j = 0; j < 2; ++j)
#pragma unroll
    for (int m = 0; m < 4; ++m) yacc[j][m] = (f32x4){0.f, 0.f, 0.f, 0.f};

  __syncthreads();   // xh ready

  const f32x4 zz = (f32x4){0.f, 0.f, 0.f, 0.f};

  for (int p = 0; p < 2; ++p) {      // two 4-head passes
    // ---- P1: QKV for heads 4p..4p+3. 24 coltiles of 16; wave owns 3 ----
    {
      f32x4 acc[3][4];
#pragma unroll
      for (int jj = 0; jj < 3; ++jj)
#pragma unroll
        for (int m = 0; m < 4; ++m) acc[jj][m] = zz;

      int gbase[3];
#pragma unroll
      for (int jj = 0; jj < 3; ++jj) {
        const int t = w * 3 + jj;
        const int kind = t >> 3, sub = t & 7;   // kind 0=Q,1=K,2=V
        gbase[jj] = (kind * 256 + p * 128 + sub * 16 + l15) * 256;
      }
      const int ko0 = khi * 8;
#pragma unroll
      for (int kt = 0; kt < 8; ++kt) {
        const int ko = kt * 32 + ko0;
        const f16x8 a0 = *(const f16x8*)&xh[SX(0 * 16 + l15, ko)];
        const f16x8 a1 = *(const f16x8*)&xh[SX(1 * 16 + l15, ko)];
        const f16x8 a2 = *(const f16x8*)&xh[SX(2 * 16 + l15, ko)];
        const f16x8 a3 = *(const f16x8*)&xh[SX(3 * 16 + l15, ko)];
#pragma unroll
        for (int jj = 0; jj < 3; ++jj) {
          const f16x8 bh = *(const f16x8*)&wqh[gbase[jj] + ko];
          const f16x8 bl = *(const f16x8*)&wql[gbase[jj] + ko];
          acc[jj][0] = mfma16(a0, bh, acc[jj][0]); acc[jj][0] = mfma16(a0, bl, acc[jj][0]);
          acc[jj][1] = mfma16(a1, bh, acc[jj][1]); acc[jj][1] = mfma16(a1, bl, acc[jj][1]);
          acc[jj][2] = mfma16(a2, bh, acc[jj][2]); acc[jj][2] = mfma16(a2, bl, acc[jj][2]);
          acc[jj][3] = mfma16(a3, bh, acc[jj][3]); acc[jj][3] = mfma16(a3, bl, acc[jj][3]);
        }
      }
      // store Q/K (scalar) and V^T (packed b64)
#pragma unroll
      for (int jj = 0; jj < 3; ++jj) {
        const int t = w * 3 + jj;
        const int kind = t >> 3, sub = t & 7;
        if (kind == 0) {
#pragma unroll
          for (int m = 0; m < 4; ++m)
#pragma unroll
            for (int rg = 0; rg < 4; ++rg)
              qk[SX(m * 16 + khi * 4 + rg, sub * 16 + l15)] = (_Float16)acc[jj][m][rg];
        } else if (kind == 1) {
#pragma unroll
          for (int m = 0; m < 4; ++m)
#pragma unroll
            for (int rg = 0; rg < 4; ++rg)
              qk[SX(m * 16 + khi * 4 + rg, 128 + sub * 16 + l15)] = (_Float16)acc[jj][m][rg];
        } else {
#pragma unroll
          for (int m = 0; m < 4; ++m) {
            f16x4 pv;
#pragma unroll
            for (int rg = 0; rg < 4; ++rg) pv[rg] = (_Float16)acc[jj][m][rg];
            *(f16x4*)&vo[SV(sub * 16 + l15, m * 16 + khi * 4)] = pv;
          }
        }
      }
    }
    __syncthreads();   // Q/K/V ready

    // ---- P2: attention; 2 waves per head (hl = w>>1, qhalf = w&1) ----
    {
      const int hl = w >> 1, qh = w & 1;
      f16x8 ka[4], qb[2];
#pragma unroll
      for (int kt = 0; kt < 4; ++kt)
        ka[kt] = *(const f16x8*)&qk[SX(kt * 16 + l15, 128 + hl * 32 + khi * 8)];
#pragma unroll
      for (int n = 0; n < 2; ++n)
        qb[n] = *(const f16x8*)&qk[SX((qh * 2 + n) * 16 + l15, hl * 32 + khi * 8)];
      __syncthreads();   // all Q/K frag reads done -> P overwrite safe

      // simT[ktok][qtok] = K·Q^T ; bias added afterwards (keeps VGPR peak low)
      f32x4 st[4][2];
#pragma unroll
      for (int kt = 0; kt < 4; ++kt)
#pragma unroll
        for (int n = 0; n < 2; ++n)
          st[kt][n] = mfma16(ka[kt], qb[n], zz);

      // + bias from global bexp (L2-hot), then softmax over ktok
#pragma unroll
      for (int n = 0; n < 2; ++n)
#pragma unroll
        for (int kt = 0; kt < 4; ++kt) {
          const f32x4 bv = *(const f32x4*)&bexp[(qh * 32 + n * 16 + l15) * 64 + kt * 16 + khi * 4];
          st[kt][n] = st[kt][n] + bv;
        }

#pragma unroll
      for (int n = 0; n < 2; ++n) {
        float mx = st[0][n][0];
#pragma unroll
        for (int kt = 0; kt < 4; ++kt)
#pragma unroll
          for (int rg = 0; rg < 4; ++rg) mx = fmaxf(mx, st[kt][n][rg]);
        mx = fmaxf(mx, __shfl_xor(mx, 16, 64));
        mx = fmaxf(mx, __shfl_xor(mx, 32, 64));
        float sm = 0.f;
#pragma unroll
        for (int kt = 0; kt < 4; ++kt)
#pragma unroll
          for (int rg = 0; rg < 4; ++rg) {
            const float e = __expf(st[kt][n][rg] - mx);
            st[kt][n][rg] = e;
            sm += e;
          }
        sm += __shfl_xor(sm, 16, 64);
        sm += __shfl_xor(sm, 32, 64);
        const float inv = 1.f / sm;
#pragma unroll
        for (int kt = 0; kt < 4; ++kt)
#pragma unroll
          for (int rg = 0; rg < 4; ++rg) st[kt][n][rg] *= inv;
      }

      // write P[qt][kt] into qk cols hl*64.. (head-disjoint), packed b64
#pragma unroll
      for (int n = 0; n < 2; ++n)
#pragma unroll
        for (int kt = 0; kt < 4; ++kt) {
          f16x4 pp;
#pragma unroll
          for (int rg = 0; rg < 4; ++rg) pp[rg] = (_Float16)st[kt][n][rg];
          *(f16x4*)&qk[SX(qh * 32 + n * 16 + l15, hl * 64 + kt * 16 + khi * 4)] = pp;
        }

      // O^T = V^T · P^T (same-wave P read-back; vt rows of own head)
      f32x4 ot[2][2];
#pragma unroll
      for (int dt = 0; dt < 2; ++dt)
#pragma unroll
        for (int n = 0; n < 2; ++n) ot[dt][n] = zz;
#pragma unroll
      for (int k2 = 0; k2 < 2; ++k2) {
        const f16x8 va0 = *(const f16x8*)&vo[SV(hl * 32 + 0 * 16 + l15, k2 * 32 + khi * 8)];
        const f16x8 va1 = *(const f16x8*)&vo[SV(hl * 32 + 1 * 16 + l15, k2 * 32 + khi * 8)];
        const f16x8 pb0 = *(const f16x8*)&qk[SX(qh * 32 + 0 * 16 + l15, hl * 64 + k2 * 32 + khi * 8)];
        const f16x8 pb1 = *(const f16x8*)&qk[SX(qh * 32 + 1 * 16 + l15, hl * 64 + k2 * 32 + khi * 8)];
        ot[0][0] = mfma16(va0, pb0, ot[0][0]);
        ot[0][1] = mfma16(va0, pb1, ot[0][1]);
        ot[1][0] = mfma16(va1, pb0, ot[1][0]);
        ot[1][1] = mfma16(va1, pb1, ot[1][1]);
      }
      __syncthreads();   // all V^T reads done -> O overwrite of vo safe

      // O[tok][hl*32+dh] into vo-as-obuf [64][128], packed b64
#pragma unroll
      for (int n = 0; n < 2; ++n)
#pragma unroll
        for (int dt = 0; dt < 2; ++dt) {
          f16x4 ov;
#pragma unroll
          for (int rg = 0; rg < 4; ++rg) ov[rg] = (_Float16)ot[dt][n][rg];
          *(f16x4*)&vo[SO(qh * 32 + n * 16 + l15, hl * 32 + dt * 16 + khi * 4)] = ov;
        }
    }
    __syncthreads();   // O ready

    // ---- P3: Y += O @ Wout (k-range p*128..p*128+127); wave owns 2 coltiles ----
    {
#pragma unroll
      for (int kt = 0; kt < 4; ++kt) {
        const int ko = kt * 32 + khi * 8;
        const f16x8 a0 = *(const f16x8*)&vo[SO(0 * 16 + l15, ko)];
        const f16x8 a1 = *(const f16x8*)&vo[SO(1 * 16 + l15, ko)];
        const f16x8 a2 = *(const f16x8*)&vo[SO(2 * 16 + l15, ko)];
        const f16x8 a3 = *(const f16x8*)&vo[SO(3 * 16 + l15, ko)];
#pragma unroll
        for (int j = 0; j < 2; ++j) {
          const int oc = (w * 2 + j) * 16 + l15;
          const int base = oc * 256 + p * 128 + ko;
          const f16x8 bh = *(const f16x8*)&woh[base];
          const f16x8 bl = *(const f16x8*)&wol[base];
          yacc[j][0] = mfma16(a0, bh, yacc[j][0]); yacc[j][0] = mfma16(a0, bl, yacc[j][0]);
          yacc[j][1] = mfma16(a1, bh, yacc[j][1]); yacc[j][1] = mfma16(a1, bl, yacc[j][1]);
          yacc[j][2] = mfma16(a2, bh, yacc[j][2]); yacc[j][2] = mfma16(a2, bl, yacc[j][2]);
          yacc[j][3] = mfma16(a3, bh, yacc[j][3]); yacc[j][3] = mfma16(a3, bl, yacc[j][3]);
        }
      }
    }
    __syncthreads();   // obuf reads done -> next pass P1 may overwrite qk/vo
  }

  // ---- epilogue: + b_out, un-window, store fp32 ----
#pragma unroll
  for (int j = 0; j < 2; ++j) {
    const int oc = (w * 2 + j) * 16 + l15;
    const float bo = bout[oc];
#pragma unroll
    for (int m = 0; m < 4; ++m)
#pragma unroll
      for (int rg = 0; rg < 4; ++rg) {
        const int tok = m * 16 + khi * 4 + rg;
        const int row = hb * 8 + (tok >> 3);
        const int col = wb * 8 + (tok & 7);
        out[(((size_t)bb_ * 128 + row) * 128 + col) * 256 + oc] = yacc[j][m][rg] + bo;
      }
  }
}

extern "C" void kernel_launch(void* const* d_in, const int* in_sizes, int n_in,
                              void* d_out, int out_size, void* d_ws, size_t ws_size,
                              hipStream_t stream) {
  const float* x    = (const float*)d_in[0];
  const float* ng   = (const float*)d_in[1];
  const float* nb   = (const float*)d_in[2];
  const float* wqkv = (const float*)d_in[3];
  const float* wout = (const float*)d_in[4];
  const float* bout = (const float*)d_in[5];
  const float* dw1  = (const float*)d_in[6];
  const float* db1  = (const float*)d_in[7];
  const float* dg1  = (const float*)d_in[8];
  const float* dbb1 = (const float*)d_in[9];
  const float* dw2  = (const float*)d_in[10];
  const float* db2  = (const float*)d_in[11];
  const float* dg2  = (const float*)d_in[12];
  const float* dbb2 = (const float*)d_in[13];
  const float* dw3  = (const float*)d_in[14];
  const float* db3  = (const float*)d_in[15];
  const float* dg3  = (const float*)d_in[16];
  const float* dbb3 = (const float*)d_in[17];
  const float* dw4  = (const float*)d_in[18];
  const float* db4  = (const float*)d_in[19];

  char* ws = (char*)d_ws;
  float* biases  = (float*)ws;                          //    2048 B (289 used)
  _Float16* wqh  = (_Float16*)(ws + 2048);              //  393216 B
  _Float16* wql  = (_Float16*)(ws + 2048 + 393216);     //  393216 B
  _Float16* woh  = (_Float16*)(ws + 2048 + 786432);     //  131072 B
  _Float16* wol  = (_Float16*)(ws + 2048 + 917504);     //  131072 B
  float* bexp    = (float*)(ws + 1050624);              //   16384 B -> 1,067,008 total

  float* out = (float*)d_out;

  dpb_kernel<<<289, 64, 0, stream>>>(dw1, db1, dg1, dbb1, dw2, db2, dg2, dbb2,
                                     dw3, db3, dg3, dbb3, dw4, db4, biases);
  expand_bias<<<64, 64, 0, stream>>>(biases, bexp);
  prep_wqkv<<<768, 256, 0, stream>>>(wqkv, wqh, wql);
  prep_wout<<<256, 256, 0, stream>>>(wout, woh, wol);
  attn_mfma3<<<2048, 512, 0, stream>>>(x, ng, nb, wqh, wql, woh, wol, bout, bexp, out);
}

// Round 10
// 656.652 us; speedup vs baseline: 1.3910x; 1.1815x over previous
//
#include <hip/hip_runtime.h>
#include <math.h>

#define ATTN_SCALE 0.17677669529663687f   // 32^-0.5

typedef __attribute__((ext_vector_type(8))) _Float16 f16x8;
typedef __attribute__((ext_vector_type(4))) _Float16 f16x4;
typedef __attribute__((ext_vector_type(4))) float f32x4;

__device__ __forceinline__ f32x4 mfma16(f16x8 a, f16x8 b, f32x4 c) {
  return __builtin_amdgcn_mfma_f32_16x16x32_f16(a, b, c, 0, 0, 0);
}

// XOR-swizzled LDS index helpers (return f16 element index); XOR touches only
// byte-bits >=4 so 16B/8B alignment is preserved.
__device__ __forceinline__ int SX(int r, int c) {  // 256 f16/row
  int b = (r << 9) + (c << 1);
  return (b ^ ((r & 7) << 4)) >> 1;
}
__device__ __forceinline__ int SV(int r, int c) {  // 64 f16/row
  int b = (r << 7) + (c << 1);
  return (b ^ ((r & 7) << 4)) >> 1;
}

__device__ __forceinline__ float wave_sum64(float v) {
#pragma unroll
  for (int m = 1; m < 64; m <<= 1) v += __shfl_xor(v, m, 64);
  return v;
}

// ---------------- dynamic position bias MLP ----------------
__global__ void dpb_kernel(const float* __restrict__ w1, const float* __restrict__ b1,
                           const float* __restrict__ g1, const float* __restrict__ bb1,
                           const float* __restrict__ w2, const float* __restrict__ b2,
                           const float* __restrict__ g2, const float* __restrict__ bb2,
                           const float* __restrict__ w3, const float* __restrict__ b3,
                           const float* __restrict__ g3, const float* __restrict__ bb3,
                           const float* __restrict__ w4, const float* __restrict__ b4,
                           float* __restrict__ biases) {
  const int r = blockIdx.x;
  const int lane = threadIdx.x;
  const float rel0 = (float)(r / 17 - 8);
  const float rel1 = (float)(r % 17 - 8);

  float h = rel0 * w1[lane] + rel1 * w1[64 + lane] + b1[lane];
  {
    const float mean = wave_sum64(h) * (1.f / 64.f);
    const float d = h - mean;
    const float var = wave_sum64(d * d) * (1.f / 64.f);
    h = fmaxf(d * rsqrtf(var + 1e-3f) * g1[lane] + bb1[lane], 0.f);
  }
  float h2 = b2[lane];
  for (int i = 0; i < 64; ++i) h2 += __shfl(h, i, 64) * w2[i * 64 + lane];
  {
    const float mean = wave_sum64(h2) * (1.f / 64.f);
    const float d = h2 - mean;
    const float var = wave_sum64(d * d) * (1.f / 64.f);
    h2 = fmaxf(d * rsqrtf(var + 1e-3f) * g2[lane] + bb2[lane], 0.f);
  }
  float h3 = b3[lane];
  for (int i = 0; i < 64; ++i) h3 += __shfl(h2, i, 64) * w3[i * 64 + lane];
  {
    const float mean = wave_sum64(h3) * (1.f / 64.f);
    const float d = h3 - mean;
    const float var = wave_sum64(d * d) * (1.f / 64.f);
    h3 = fmaxf(d * rsqrtf(var + 1e-3f) * g3[lane] + bb3[lane], 0.f);
  }
  float p = wave_sum64(h3 * w4[lane]);
  if (lane == 0) biases[r] = p + b4[0];
}

// ---------------- weight prep: coalesced LDS transpose + fp16 hi/lo split ----
// blocks 0..47: wqkv[256][768] -> wqh/wql[768][256] (Q cols pre-scaled)
// blocks 48..63: wout[256][256] -> woh/wol[256][256]
__global__ void prep_t(const float* __restrict__ wqkv, const float* __restrict__ wout,
                       _Float16* __restrict__ wqh, _Float16* __restrict__ wql,
                       _Float16* __restrict__ woh, _Float16* __restrict__ wol) {
  __shared__ float tile[64][65];
  const int bid = blockIdx.x;
  const bool A = bid < 48;
  const int lt = A ? bid : bid - 48;
  const int kt = A ? lt / 12 : lt / 4;
  const int ot = A ? lt % 12 : lt % 4;
  const int K0 = kt * 64, O0 = ot * 64;
  const float* src = A ? wqkv : wout;
  const int ld = A ? 768 : 256;
  _Float16* th = A ? wqh : woh;
  _Float16* tl = A ? wql : wol;
  const int x = threadIdx.x & 63;
  const int ty = threadIdx.x >> 6;  // 0..3
#pragma unroll
  for (int yy = 0; yy < 16; ++yy) {
    const int kk = ty * 16 + yy;
    tile[kk][x] = src[(K0 + kk) * ld + O0 + x];   // coalesced 256B rows
  }
  __syncthreads();
#pragma unroll
  for (int yy = 0; yy < 16; ++yy) {
    const int oo = ty * 16 + yy;
    float v = tile[x][oo];                        // bank-safe (stride 65)
    if (A && (O0 + oo) < 256) v *= ATTN_SCALE;
    const _Float16 hi = (_Float16)v;
    th[(O0 + oo) * 256 + K0 + x] = hi;            // coalesced writes
    tl[(O0 + oo) * 256 + K0 + x] = (_Float16)(v - (float)hi);
  }
}

// ---------------- K12: fused LN + QKV + attention (no out-proj) ----------------
// 1 window/block, 512 threads = 8 waves, 80 KB LDS. O (fp16, un-windowed) goes
// to the first 512B of each spatial token's 1KB slot in d_out.
__global__ __launch_bounds__(512, 2) void attn_qkv(
    const float* __restrict__ x, const float* __restrict__ gamma,
    const float* __restrict__ beta,
    const _Float16* __restrict__ wqh, const _Float16* __restrict__ wql,
    const float* __restrict__ biases, float* __restrict__ out) {
  __shared__ __align__(16) _Float16 smem[40960];   // 81920 B
  _Float16* xh = smem;            // [64][256] LN'd x (SX)
  _Float16* qk = smem + 16384;    // [64][256] Q|K -> P (SX)
  _Float16* vt = smem + 32768;    // [128][64] V^T of pass (SV)
  _Float16* obuf = (_Float16*)out;

  const int tid = threadIdx.x;
  const int lane = tid & 63;
  const int w = tid >> 6;
  const int l15 = lane & 15;
  const int khi = lane >> 4;

  const int wi = blockIdx.x;
  const int bb_ = wi >> 8;
  const int hb = (wi >> 4) & 15;
  const int wb = wi & 15;

  // ---- LN (eps 1e-5) -> xh fp16 ----
  {
    const int t = tid >> 3;
    const int d0 = (tid & 7) * 32;
    const int row = hb * 8 + (t >> 3);
    const int col = wb * 8 + (t & 7);
    const float* gp = x + ((((size_t)bb_ * 128 + row) * 128 + col) * 256 + d0);
    float vv[32];
    float sum = 0.f, ssq = 0.f;
#pragma unroll
    for (int j = 0; j < 8; ++j) {
      const float4 v4 = *(const float4*)(gp + j * 4);
      vv[j * 4 + 0] = v4.x; vv[j * 4 + 1] = v4.y;
      vv[j * 4 + 2] = v4.z; vv[j * 4 + 3] = v4.w;
      sum += v4.x + v4.y + v4.z + v4.w;
      ssq += v4.x * v4.x + v4.y * v4.y + v4.z * v4.z + v4.w * v4.w;
    }
#pragma unroll
    for (int mm = 1; mm < 8; mm <<= 1) {
      sum += __shfl_xor(sum, mm, 64);
      ssq += __shfl_xor(ssq, mm, 64);
    }
    const float mean = sum * (1.f / 256.f);
    const float var = ssq * (1.f / 256.f) - mean * mean;
    const float rstd = rsqrtf(var + 1e-5f);
#pragma unroll
    for (int q = 0; q < 8; ++q) {
      const float4 g4 = *(const float4*)(gamma + d0 + q * 4);
      const float4 b4 = *(const float4*)(beta + d0 + q * 4);
      vv[q * 4 + 0] = (vv[q * 4 + 0] - mean) * rstd * g4.x + b4.x;
      vv[q * 4 + 1] = (vv[q * 4 + 1] - mean) * rstd * g4.y + b4.y;
      vv[q * 4 + 2] = (vv[q * 4 + 2] - mean) * rstd * g4.z + b4.z;
      vv[q * 4 + 3] = (vv[q * 4 + 3] - mean) * rstd * g4.w + b4.w;
    }
#pragma unroll
    for (int q = 0; q < 4; ++q) {
      f16x8 pk;
#pragma unroll
      for (int e = 0; e < 8; ++e) pk[e] = (_Float16)vv[q * 8 + e];
      *(f16x8*)&xh[SX(t, d0 + q * 8)] = pk;
    }
  }

  __syncthreads();   // xh ready
  const f32x4 zz = (f32x4){0.f, 0.f, 0.f, 0.f};

  for (int p = 0; p < 2; ++p) {      // two 4-head passes
    // ---- P1: QKV for heads 4p..4p+3; wave owns 3 of 24 coltiles ----
    {
      f32x4 acc[3][4];
#pragma unroll
      for (int jj = 0; jj < 3; ++jj)
#pragma unroll
        for (int m = 0; m < 4; ++m) acc[jj][m] = zz;

      int gbase[3];
#pragma unroll
      for (int jj = 0; jj < 3; ++jj) {
        const int t = w * 3 + jj;
        const int kind = t >> 3, sub = t & 7;   // 0=Q,1=K,2=V
        gbase[jj] = (kind * 256 + p * 128 + sub * 16 + l15) * 256;
      }
      const int ko0 = khi * 8;
#pragma unroll
      for (int kt = 0; kt < 8; ++kt) {
        const int ko = kt * 32 + ko0;
        const f16x8 a0 = *(const f16x8*)&xh[SX(0 * 16 + l15, ko)];
        const f16x8 a1 = *(const f16x8*)&xh[SX(1 * 16 + l15, ko)];
        const f16x8 a2 = *(const f16x8*)&xh[SX(2 * 16 + l15, ko)];
        const f16x8 a3 = *(const f16x8*)&xh[SX(3 * 16 + l15, ko)];
#pragma unroll
        for (int jj = 0; jj < 3; ++jj) {
          const f16x8 bh = *(const f16x8*)&wqh[gbase[jj] + ko];
          const f16x8 bl = *(const f16x8*)&wql[gbase[jj] + ko];
          acc[jj][0] = mfma16(a0, bh, acc[jj][0]); acc[jj][0] = mfma16(a0, bl, acc[jj][0]);
          acc[jj][1] = mfma16(a1, bh, acc[jj][1]); acc[jj][1] = mfma16(a1, bl, acc[jj][1]);
          acc[jj][2] = mfma16(a2, bh, acc[jj][2]); acc[jj][2] = mfma16(a2, bl, acc[jj][2]);
          acc[jj][3] = mfma16(a3, bh, acc[jj][3]); acc[jj][3] = mfma16(a3, bl, acc[jj][3]);
        }
      }
#pragma unroll
      for (int jj = 0; jj < 3; ++jj) {
        const int t = w * 3 + jj;
        const int kind = t >> 3, sub = t & 7;
        if (kind == 0) {
#pragma unroll
          for (int m = 0; m < 4; ++m)
#pragma unroll
            for (int rg = 0; rg < 4; ++rg)
              qk[SX(m * 16 + khi * 4 + rg, sub * 16 + l15)] = (_Float16)acc[jj][m][rg];
        } else if (kind == 1) {
#pragma unroll
          for (int m = 0; m < 4; ++m)
#pragma unroll
            for (int rg = 0; rg < 4; ++rg)
              qk[SX(m * 16 + khi * 4 + rg, 128 + sub * 16 + l15)] = (_Float16)acc[jj][m][rg];
        } else {
#pragma unroll
          for (int m = 0; m < 4; ++m) {
            f16x4 pv;
#pragma unroll
            for (int rg = 0; rg < 4; ++rg) pv[rg] = (_Float16)acc[jj][m][rg];
            *(f16x4*)&vt[SV(sub * 16 + l15, m * 16 + khi * 4)] = pv;
          }
        }
      }
    }
    __syncthreads();   // Q/K/V ready

    // ---- P2: attention; 2 waves per head (hl = w>>1, qh = w&1) ----
    {
      const int hl = w >> 1, qh = w & 1;
      f16x8 ka[4], qb[2];
#pragma unroll
      for (int kt = 0; kt < 4; ++kt)
        ka[kt] = *(const f16x8*)&qk[SX(kt * 16 + l15, 128 + hl * 32 + khi * 8)];
#pragma unroll
      for (int n = 0; n < 2; ++n)
        qb[n] = *(const f16x8*)&qk[SX((qh * 2 + n) * 16 + l15, hl * 32 + khi * 8)];
      __syncthreads();   // all Q/K frag reads done -> P overwrite safe

      // simT[ktok][qtok] = K·Q^T
      f32x4 st[4][2];
#pragma unroll
      for (int kt = 0; kt < 4; ++kt)
#pragma unroll
        for (int n = 0; n < 2; ++n)
          st[kt][n] = mfma16(ka[kt], qb[n], zz);

      // + bias gathered inline from 289-entry table (L1-hot)
#pragma unroll
      for (int n = 0; n < 2; ++n) {
        const int qt = qh * 32 + n * 16 + l15;
#pragma unroll
        for (int kt = 0; kt < 4; ++kt)
#pragma unroll
          for (int rg = 0; rg < 4; ++rg) {
            const int kk = kt * 16 + khi * 4 + rg;
            const int idx = ((qt >> 3) - (kk >> 3) + 7) * 15 + ((qt & 7) - (kk & 7) + 7);
            st[kt][n][rg] += biases[idx];
          }
      }

      // softmax over ktok: 16 in-lane + khi-group shuffles
#pragma unroll
      for (int n = 0; n < 2; ++n) {
        float mx = st[0][n][0];
#pragma unroll
        for (int kt = 0; kt < 4; ++kt)
#pragma unroll
          for (int rg = 0; rg < 4; ++rg) mx = fmaxf(mx, st[kt][n][rg]);
        mx = fmaxf(mx, __shfl_xor(mx, 16, 64));
        mx = fmaxf(mx, __shfl_xor(mx, 32, 64));
        float sm = 0.f;
#pragma unroll
        for (int kt = 0; kt < 4; ++kt)
#pragma unroll
          for (int rg = 0; rg < 4; ++rg) {
            const float e = __expf(st[kt][n][rg] - mx);
            st[kt][n][rg] = e;
            sm += e;
          }
        sm += __shfl_xor(sm, 16, 64);
        sm += __shfl_xor(sm, 32, 64);
        const float inv = 1.f / sm;
#pragma unroll
        for (int kt = 0; kt < 4; ++kt)
#pragma unroll
          for (int rg = 0; rg < 4; ++rg) st[kt][n][rg] *= inv;
      }

      // write P[qt][kt] into qk cols hl*64.. (wave-private), packed b64
#pragma unroll
      for (int n = 0; n < 2; ++n)
#pragma unroll
        for (int kt = 0; kt < 4; ++kt) {
          f16x4 pp;
#pragma unroll
          for (int rg = 0; rg < 4; ++rg) pp[rg] = (_Float16)st[kt][n][rg];
          *(f16x4*)&qk[SX(qh * 32 + n * 16 + l15, hl * 64 + kt * 16 + khi * 4)] = pp;
        }

      // O^T = V^T · P^T (same-wave P read-back)
      f32x4 ot[2][2];
#pragma unroll
      for (int dt = 0; dt < 2; ++dt)
#pragma unroll
        for (int n = 0; n < 2; ++n) ot[dt][n] = zz;
#pragma unroll
      for (int k2 = 0; k2 < 2; ++k2) {
        const f16x8 va0 = *(const f16x8*)&vt[SV(hl * 32 + 0 * 16 + l15, k2 * 32 + khi * 8)];
        const f16x8 va1 = *(const f16x8*)&vt[SV(hl * 32 + 1 * 16 + l15, k2 * 32 + khi * 8)];
        const f16x8 pb0 = *(const f16x8*)&qk[SX(qh * 32 + 0 * 16 + l15, hl * 64 + k2 * 32 + khi * 8)];
        const f16x8 pb1 = *(const f16x8*)&qk[SX(qh * 32 + 1 * 16 + l15, hl * 64 + k2 * 32 + khi * 8)];
        ot[0][0] = mfma16(va0, pb0, ot[0][0]);
        ot[0][1] = mfma16(va0, pb1, ot[0][1]);
        ot[1][0] = mfma16(va1, pb0, ot[1][0]);
        ot[1][1] = mfma16(va1, pb1, ot[1][1]);
      }

      // store O (fp16) un-windowed into d_out slots: token s gets 512B at s*1KB
#pragma unroll
      for (int n = 0; n < 2; ++n) {
        const int tok = qh * 32 + n * 16 + l15;
        const int t1 = tok >> 3, t2 = tok & 7;
        const size_t s = ((size_t)bb_ * 128 + hb * 8 + t1) * 128 + wb * 8 + t2;
#pragma unroll
        for (int dt = 0; dt < 2; ++dt) {
          const int d = p * 128 + hl * 32 + dt * 16 + khi * 4;
          f16x4 ov;
#pragma unroll
          for (int rg = 0; rg < 4; ++rg) ov[rg] = (_Float16)ot[dt][n][rg];
          *(f16x4*)&obuf[s * 512 + d] = ov;
        }
      }
    }
    __syncthreads();   // protect qk/vt before next pass P1
  }
}

// ---------------- K3: out-projection GEMM ----------------
// block = 64 consecutive spatial tokens; stages own O slots -> LDS, computes
// O@Wout + bias, overwrites the same slots with final f32.
__global__ __launch_bounds__(512, 2) void out_proj(
    const _Float16* __restrict__ woh, const _Float16* __restrict__ wol,
    const float* __restrict__ bout, float* __restrict__ out) {
  __shared__ __align__(16) _Float16 os[16384];   // [64][256] 32 KiB (SX)
  const _Float16* obuf = (const _Float16*)out;

  const int tid = threadIdx.x;
  const int lane = tid & 63;
  const int w = tid >> 6;
  const int l15 = lane & 15;
  const int khi = lane >> 4;
  const int S0 = blockIdx.x * 64;

  // stage O tile (reads only this block's slots)
  {
    const int r = tid >> 3;
    const int c = (tid & 7) * 32;
    const _Float16* src = obuf + (size_t)(S0 + r) * 512 + c;
#pragma unroll
    for (int q = 0; q < 4; ++q) {
      const f16x8 v = *(const f16x8*)(src + q * 8);
      *(f16x8*)&os[SX(r, c + q * 8)] = v;
    }
  }
  __syncthreads();

  const f32x4 zz = (f32x4){0.f, 0.f, 0.f, 0.f};
  f32x4 acc[2][4];
#pragma unroll
  for (int j = 0; j < 2; ++j)
#pragma unroll
    for (int m = 0; m < 4; ++m) acc[j][m] = zz;

#pragma unroll
  for (int kt = 0; kt < 8; ++kt) {
    const int ko = kt * 32 + khi * 8;
    const f16x8 a0 = *(const f16x8*)&os[SX(0 * 16 + l15, ko)];
    const f16x8 a1 = *(const f16x8*)&os[SX(1 * 16 + l15, ko)];
    const f16x8 a2 = *(const f16x8*)&os[SX(2 * 16 + l15, ko)];
    const f16x8 a3 = *(const f16x8*)&os[SX(3 * 16 + l15, ko)];
#pragma unroll
    for (int j = 0; j < 2; ++j) {
      const int oc = (w * 2 + j) * 16 + l15;
      const int base = oc * 256 + ko;
      const f16x8 bh = *(const f16x8*)&woh[base];
      const f16x8 bl = *(const f16x8*)&wol[base];
      acc[j][0] = mfma16(a0, bh, acc[j][0]); acc[j][0] = mfma16(a0, bl, acc[j][0]);
      acc[j][1] = mfma16(a1, bh, acc[j][1]); acc[j][1] = mfma16(a1, bl, acc[j][1]);
      acc[j][2] = mfma16(a2, bh, acc[j][2]); acc[j][2] = mfma16(a2, bl, acc[j][2]);
      acc[j][3] = mfma16(a3, bh, acc[j][3]); acc[j][3] = mfma16(a3, bl, acc[j][3]);
    }
  }

  // epilogue: + bias, overwrite slots with f32 (token order is already spatial)
#pragma unroll
  for (int j = 0; j < 2; ++j) {
    const int oc = (w * 2 + j) * 16 + l15;
    const float bo = bout[oc];
#pragma unroll
    for (int m = 0; m < 4; ++m)
#pragma unroll
      for (int rg = 0; rg < 4; ++rg) {
        const int tok = m * 16 + khi * 4 + rg;
        out[(size_t)(S0 + tok) * 256 + oc] = acc[j][m][rg] + bo;
      }
  }
}

extern "C" void kernel_launch(void* const* d_in, const int* in_sizes, int n_in,
                              void* d_out, int out_size, void* d_ws, size_t ws_size,
                              hipStream_t stream) {
  const float* x    = (const float*)d_in[0];
  const float* ng   = (const float*)d_in[1];
  const float* nb   = (const float*)d_in[2];
  const float* wqkv = (const float*)d_in[3];
  const float* wout = (const float*)d_in[4];
  const float* bout = (const float*)d_in[5];
  const float* dw1  = (const float*)d_in[6];
  const float* db1  = (const float*)d_in[7];
  const float* dg1  = (const float*)d_in[8];
  const float* dbb1 = (const float*)d_in[9];
  const float* dw2  = (const float*)d_in[10];
  const float* db2  = (const float*)d_in[11];
  const float* dg2  = (const float*)d_in[12];
  const float* dbb2 = (const float*)d_in[13];
  const float* dw3  = (const float*)d_in[14];
  const float* db3  = (const float*)d_in[15];
  const float* dg3  = (const float*)d_in[16];
  const float* dbb3 = (const float*)d_in[17];
  const float* dw4  = (const float*)d_in[18];
  const float* db4  = (const float*)d_in[19];

  char* ws = (char*)d_ws;
  float* biases  = (float*)ws;                          //    2048 B (289 used)
  _Float16* wqh  = (_Float16*)(ws + 2048);              //  393216 B
  _Float16* wql  = (_Float16*)(ws + 2048 + 393216);     //  393216 B
  _Float16* woh  = (_Float16*)(ws + 2048 + 786432);     //  131072 B
  _Float16* wol  = (_Float16*)(ws + 2048 + 917504);     //  131072 B -> 1,050,624 total

  float* out = (float*)d_out;

  dpb_kernel<<<289, 64, 0, stream>>>(dw1, db1, dg1, dbb1, dw2, db2, dg2, dbb2,
                                     dw3, db3, dg3, dbb3, dw4, db4, biases);
  prep_t<<<64, 256, 0, stream>>>(wqkv, wout, wqh, wql, woh, wol);
  attn_qkv<<<2048, 512, 0, stream>>>(x, ng, nb, wqh, wql, biases, out);
  out_proj<<<2048, 512, 0, stream>>>(woh, wol, bout, out);
}